// Round 6
// baseline (251.282 us; speedup 1.0000x reference)
//
#include <hip/hip_runtime.h>
#include <cstdint>
#include <cstddef>

// Problem constants: B=2, S=2048, D=1024, H=16, dk=64. M = B*S = 4096.
#define S_LEN 2048
#define NH    16
#define DKH   64
#define DEMB  1024
#define MTOT  4096

typedef float f32x4 __attribute__((ext_vector_type(4)));
typedef __bf16 bf16x8 __attribute__((ext_vector_type(8)));
typedef unsigned short u16;
typedef unsigned int u32;
typedef u16 u16x8 __attribute__((ext_vector_type(8)));
typedef u16 u16x4 __attribute__((ext_vector_type(4)));
typedef u32 u32x2 __attribute__((ext_vector_type(2)));

static __device__ __forceinline__ u16 f2bf(float f) {
  u32 u = __builtin_bit_cast(u32, f);
  u += 0x7fffu + ((u >> 16) & 1u);          // RNE
  return (u16)(u >> 16);
}
static __device__ __forceinline__ float bf2f(u16 b) {
  return __builtin_bit_cast(float, ((u32)b) << 16);
}
static __device__ __forceinline__ bf16x8 ldfrag(const u16* p) {
  return __builtin_bit_cast(bf16x8, *(const u16x8*)p);
}
static __device__ __forceinline__ f32x4 mfma16(bf16x8 a, bf16x8 b, f32x4 c) {
  return __builtin_amdgcn_mfma_f32_16x16x32_bf16(a, b, c, 0, 0, 0);
}
static __device__ __forceinline__ void gl2lds16(const void* g, void* l) {
  __builtin_amdgcn_global_load_lds((__attribute__((address_space(1))) void*)g,
                                   (__attribute__((address_space(3))) void*)l,
                                   16, 0, 0);
}
// pack two fp32 -> two bf16 (round-half-up) in one v_perm
static __device__ __forceinline__ u32 pkbf(float hi, float lo) {
  u32 a = __builtin_bit_cast(u32, hi) + 0x8000u;
  u32 b = __builtin_bit_cast(u32, lo) + 0x8000u;
  return __builtin_amdgcn_perm(a, b, 0x07060302u);
}

// 1/sqrt(dk) * log2(e): folded into the Q projection so attention scores are
// already in the exp2 domain.
#define SCL_Q (0.125f * 1.44269504088896340736f)

// ---------------- fp32 -> bf16 convert (weights + activations) ----------------
__global__ __launch_bounds__(256) void cvt_bf16(const float* __restrict__ s,
                                                u16* __restrict__ d, int n) {
  int i = (blockIdx.x * 256 + threadIdx.x) * 4;
  if (i >= n) return;
  f32x4 f = *(const f32x4*)(s + i);
  u16x4 o;
  o[0] = f2bf(f[0]); o[1] = f2bf(f[1]); o[2] = f2bf(f[2]); o[3] = f2bf(f[3]);
  *(u16x4*)(d + i) = o;
}

// ---------------- fused QKV projection GEMM (pure bf16, m97 structure) -------
__global__ __launch_bounds__(256) void qkv_gemm(
    const u16* __restrict__ qin, const u16* __restrict__ kin,
    const u16* __restrict__ vin, const u16* __restrict__ W,
    const float* __restrict__ bq, const float* __restrict__ bk,
    const float* __restrict__ bv,
    u16* __restrict__ qh, u16* __restrict__ kh, u16* __restrict__ vt) {
  __shared__ __align__(16) u16 sA[128 * 32];    // 8 KB
  __shared__ __align__(16) u16 sB[128 * 32];    // 8 KB
  const int t = threadIdx.x;
  const int l = t & 63, w = t >> 6;
  const int ll = l & 15, lg = l >> 4;
  const int nb = blockIdx.x;           // 0..23 (N = 3072)
  const int mb = blockIdx.y;           // 0..31 (M = 4096)
  const int which = nb >> 3;           // 0=Q,1=K,2=V
  const u16* A = (which == 0) ? qin : ((which == 1) ? kin : vin);
  const int wr = (w >> 1) * 64, wc = (w & 1) * 64;

  f32x4 acc[4][4] = {};

  for (int kt = 0; kt < 32; ++kt) {
    const int k0 = kt * 32;
    __syncthreads();
#pragma unroll
    for (int i = 0; i < 2; ++i) {
      const int c = i * 256 + t;                 // 16B chunk 0..511
      const int row = c >> 2;                    // 0..127
      const int gc = (c & 3) ^ ((row >> 1) & 3); // global col-chunk
      gl2lds16(A + (size_t)(mb * 128 + row) * DEMB + k0 + gc * 8, &sA[c * 8]);
      gl2lds16(W + (size_t)(nb * 128 + row) * DEMB + k0 + gc * 8, &sB[c * 8]);
    }
    __syncthreads();

    bf16x8 af[4], bfr[4];
#pragma unroll
    for (int i2 = 0; i2 < 4; ++i2) {
      const int row = wr + i2 * 16 + ll;
      af[i2] = ldfrag(&sA[row * 32 + (lg ^ ((row >> 1) & 3)) * 8]);
    }
#pragma unroll
    for (int j2 = 0; j2 < 4; ++j2) {
      const int row = wc + j2 * 16 + ll;
      bfr[j2] = ldfrag(&sB[row * 32 + (lg ^ ((row >> 1) & 3)) * 8]);
    }
#pragma unroll
    for (int i2 = 0; i2 < 4; ++i2)
#pragma unroll
      for (int j2 = 0; j2 < 4; ++j2)
        acc[i2][j2] = mfma16(af[i2], bfr[j2], acc[i2][j2]);
  }

  const float* bias = (which == 0) ? bq : ((which == 1) ? bk : bv);
  const int b = (mb * 128) >> 11;                // tile never crosses batch

  if (which == 2) {
    // V: register scatter to [bh][dk][s]; 4 consecutive s per u16x4 store
#pragma unroll
    for (int j2 = 0; j2 < 4; ++j2) {
      const int nl = (nb * 128 + wc + j2 * 16 + ll) & 1023;
      const int h = nl >> 6, dk = nl & 63;
      const float bb = bias[nl];
      u16* base = vt + ((size_t)((b * NH + h) * DKH + dk)) * S_LEN;
#pragma unroll
      for (int i2 = 0; i2 < 4; ++i2) {
        const int s = (mb * 128 + wr + i2 * 16 + lg * 4) & 2047;
        u16x4 pk;
#pragma unroll
        for (int r = 0; r < 4; ++r) pk[r] = f2bf(acc[i2][j2][r] + bb);
        *(u16x4*)&base[s] = pk;
      }
    }
  } else {
    u16* outp = (which == 0) ? qh : kh;
    const float scl = (which == 0) ? SCL_Q : 1.0f;
#pragma unroll
    for (int j2 = 0; j2 < 4; ++j2) {
      const int nl = (nb * 128 + wc + j2 * 16 + ll) & 1023;
      const int h = nl >> 6, dk = nl & 63;
      const float bb = bias[nl];
#pragma unroll
      for (int i2 = 0; i2 < 4; ++i2) {
#pragma unroll
        for (int r = 0; r < 4; ++r) {
          const int s = (mb * 128 + wr + i2 * 16 + lg * 4 + r) & 2047;
          const float val = (acc[i2][j2][r] + bb) * scl;
          outp[((size_t)((b * NH + h) * S_LEN + s)) * DKH + dk] = f2bf(val);
        }
      }
    }
  }
}

// ---------------- flash attention, 2-way key-split partials ----------------
// Grid (32,32): x = qb*2 + ks (qb = 16 q-blocks of 128, ks = key half),
// y = bh. Each block: 128 q rows x keys [ks*1024, ks*1024+1024), KT=64.
// Fixed-max exp2 softmax => partials merge ADDITIVELY (O=O0+O1, l=l0+l1),
// no rescale — this is what makes the key-split cheap.
// Outputs: opart[ks][bh][s][dk] (bf16, unnormalized), lpart[ks][bh][s] (f32).
// LDS = 8K(sK) + 8K(sV) + 17K(sP) = 33,792 B -> 4 blocks/CU co-resident
// (grid 1024 = exactly 4/CU), 16 waves/CU vs R5's 8 (latency-bound fix).
// sP banking: row stride 68 u16 -> conflict-free writes/reads (R5, measured 0).
__global__ __launch_bounds__(256) void attn_kernel(
    const u16* __restrict__ qh, const u16* __restrict__ kh,
    const u16* __restrict__ vt, u16* __restrict__ opart,
    float* __restrict__ lpart) {
  __shared__ __align__(16) u16 sK[64 * 64];       // [key][dk]  8 KB
  __shared__ __align__(16) u16 sV[64 * 64];       // [dk][key]  8 KB
  __shared__ __align__(16) u16 sP[4][2][16 * 68]; // per-(wave,qt) [q][64key+pad]
  const int t = threadIdx.x;
  const int l = t & 63, w = t >> 6;
  const int ll = l & 15, lg = l >> 4;
  const int qb = blockIdx.x >> 1;
  const int ks = blockIdx.x & 1;
  const int q_blk = qb * 128;
  const int bh = blockIdx.y;

  // Q fragments (B-operand layout == A layout: q=ll, dk=f*32+lg*8..+7)
  bf16x8 aq[2][2];
#pragma unroll
  for (int qt = 0; qt < 2; ++qt) {
    const u16* qbase = qh + ((size_t)bh * S_LEN + q_blk + w * 32 + qt * 16 + ll) * DKH;
    aq[qt][0] = ldfrag(qbase + lg * 8);
    aq[qt][1] = ldfrag(qbase + 32 + lg * 8);
  }

  f32x4 oT[2][4] = {};        // [qt][dk-tile]; C layout: col=q=ll, row=dk
  float l_part[2] = {0.f, 0.f};

  u16* sP0 = &sP[w][0][0];
  u16* sP1 = &sP[w][1][0];

  for (int kt = 0; kt < 16; ++kt) {
    const int kb0 = ks * 1024 + kt * 64;
    __syncthreads();
#pragma unroll
    for (int i = 0; i < 2; ++i) {
      const int c = i * 256 + t;                  // 16B chunk 0..511
      const int row = c >> 3, gc = (c & 7) ^ (row & 7);
      // sK: [key row 0..63][8 chunks], swizzle chunk ^ (row&7)
      gl2lds16(kh + ((size_t)bh * S_LEN + kb0 + row) * DKH + gc * 8,
               &sK[c * 8]);
      // sV: [dk row 0..63][8 chunks of keys], swizzle chunk ^ (row&7)
      gl2lds16(vt + ((size_t)bh * DKH + row) * S_LEN + kb0 + gc * 8,
               &sV[c * 8]);
    }
    __syncthreads();

    // ---- S^T + P^T for the 64-key tile ----
#pragma unroll
    for (int kbl = 0; kbl < 4; ++kbl) {
      const int krow = kbl * 16 + ll;
      const bf16x8 ak0 = ldfrag(&sK[krow * 64 + (lg ^ (ll & 7)) * 8]);
      const bf16x8 ak1 = ldfrag(&sK[krow * 64 + ((4 + lg) ^ (ll & 7)) * 8]);
      f32x4 s0 = {}, s1 = {};
      s0 = mfma16(ak0, aq[0][0], s0);
      s0 = mfma16(ak1, aq[0][1], s0);
      s1 = mfma16(ak0, aq[1][0], s1);
      s1 = mfma16(ak1, aq[1][1], s1);
      const int poff = ll * 68 + kbl * 16 + lg * 4;   // u16 units, 8B aligned
      {
        const float p0 = __builtin_amdgcn_exp2f(s0[0]);
        const float p1 = __builtin_amdgcn_exp2f(s0[1]);
        const float p2 = __builtin_amdgcn_exp2f(s0[2]);
        const float p3 = __builtin_amdgcn_exp2f(s0[3]);
        l_part[0] += (p0 + p1) + (p2 + p3);
        u32x2 pk; pk[0] = pkbf(p1, p0); pk[1] = pkbf(p3, p2);
        *(u32x2*)&sP0[poff] = pk;
      }
      {
        const float p0 = __builtin_amdgcn_exp2f(s1[0]);
        const float p1 = __builtin_amdgcn_exp2f(s1[1]);
        const float p2 = __builtin_amdgcn_exp2f(s1[2]);
        const float p3 = __builtin_amdgcn_exp2f(s1[3]);
        l_part[1] += (p0 + p1) + (p2 + p3);
        u32x2 pk; pk[0] = pkbf(p1, p0); pk[1] = pkbf(p3, p2);
        *(u32x2*)&sP1[poff] = pk;
      }
    }

    // ---- O^T += V^T . P^T (intra-wave LDS ordering, no barrier needed) ----
    bf16x8 bp[2][2];
#pragma unroll
    for (int fl = 0; fl < 2; ++fl) {
      const int off = ll * 68 + fl * 32 + lg * 8;
      const u16x4 lo0 = *(const u16x4*)&sP0[off];
      const u16x4 hi0 = *(const u16x4*)&sP0[off + 4];
      bp[0][fl] = __builtin_bit_cast(bf16x8,
          __builtin_shufflevector(lo0, hi0, 0, 1, 2, 3, 4, 5, 6, 7));
      const u16x4 lo1 = *(const u16x4*)&sP1[off];
      const u16x4 hi1 = *(const u16x4*)&sP1[off + 4];
      bp[1][fl] = __builtin_bit_cast(bf16x8,
          __builtin_shufflevector(lo1, hi1, 0, 1, 2, 3, 4, 5, 6, 7));
    }
#pragma unroll
    for (int nt = 0; nt < 4; ++nt) {
      const int vrow = nt * 16 + ll;
#pragma unroll
      for (int fl = 0; fl < 2; ++fl) {
        const bf16x8 av = ldfrag(&sV[vrow * 64 + ((fl * 4 + lg) ^ (vrow & 7)) * 8]);
        oT[0][nt] = mfma16(av, bp[0][fl], oT[0][nt]);
        oT[1][nt] = mfma16(av, bp[1][fl], oT[1][nt]);
      }
    }
  }

  // ---- store unnormalized partials ----
#pragma unroll
  for (int qt = 0; qt < 2; ++qt) {
    float lv = l_part[qt];
    lv += __shfl_xor(lv, 16, 64);
    lv += __shfl_xor(lv, 32, 64);
    const int srow = q_blk + w * 32 + qt * 16 + ll;
    u16* obase = opart + (((size_t)(ks * 32 + bh)) * S_LEN + srow) * DKH;
#pragma unroll
    for (int nt = 0; nt < 4; ++nt) {
      u16x4 o;
#pragma unroll
      for (int r = 0; r < 4; ++r) o[r] = f2bf(oT[qt][nt][r]);
      *(u16x4*)&obase[nt * 16 + lg * 4] = o;
    }
    if (lg == 0) lpart[(ks * 32 + bh) * S_LEN + srow] = lv;
  }
}

// ---------------- merge partials -> ctx ----------------
// ctx[b][s][h][dk] = (O0 + O1) / (l0 + l1)
__global__ __launch_bounds__(256) void merge_ctx(
    const u16* __restrict__ op, const float* __restrict__ lp,
    u16* __restrict__ ctx) {
  const int idx = blockIdx.x * 256 + threadIdx.x;   // 0..524287
  const int dk8 = idx & 7;
  const int q = (idx >> 3) & 2047;
  const int bh = idx >> 14;                         // 0..31
  const float inv = 1.0f / (lp[bh * S_LEN + q] + lp[(32 + bh) * S_LEN + q]);
  const u16x8 a = *(const u16x8*)&op[((size_t)bh * S_LEN + q) * DKH + dk8 * 8];
  const u16x8 c = *(const u16x8*)&op[((size_t)(32 + bh) * S_LEN + q) * DKH + dk8 * 8];
  u16x8 o;
#pragma unroll
  for (int r = 0; r < 8; ++r) o[r] = f2bf((bf2f(a[r]) + bf2f(c[r])) * inv);
  const int b = bh >> 4, h = bh & 15;
  *(u16x8*)&ctx[((size_t)((b * S_LEN + q) * NH + h)) * DKH + dk8 * 8] = o;
}

// ---------------- output projection GEMM ----------------
// 64x64 tile, BK=64, 4 waves (2x2 of 32x32). Grid (16,64) = 1024 blocks
// = 4 blocks/CU -> ~16 waves/CU for latency hiding.
__global__ __launch_bounds__(256) void out_gemm(
    const u16* __restrict__ Am, const u16* __restrict__ W,
    const float* __restrict__ bo, float* __restrict__ out) {
  __shared__ __align__(16) u16 sA[64 * 64];   // 8 KB
  __shared__ __align__(16) u16 sB[64 * 64];   // 8 KB
  const int t = threadIdx.x;
  const int l = t & 63, w = t >> 6;
  const int ll = l & 15, lg = l >> 4;
  const int nb = blockIdx.x;  // 0..15
  const int mb = blockIdx.y;  // 0..63
  const int wr = (w >> 1) * 32, wc = (w & 1) * 32;

  f32x4 acc[2][2] = {};
  for (int kt = 0; kt < 16; ++kt) {
    const int k0 = kt * 64;
    __syncthreads();
#pragma unroll
    for (int i = 0; i < 2; ++i) {
      const int c = i * 256 + t;               // 512 chunks per buffer
      const int row = c >> 3;
      const int gc = (c & 7) ^ (row & 7);
      gl2lds16(Am + (size_t)(mb * 64 + row) * DEMB + k0 + gc * 8, &sA[c * 8]);
      gl2lds16(W + (size_t)(nb * 64 + row) * DEMB + k0 + gc * 8, &sB[c * 8]);
    }
    __syncthreads();
#pragma unroll
    for (int sub = 0; sub < 2; ++sub) {
      bf16x8 af[2], bfr[2];
#pragma unroll
      for (int i2 = 0; i2 < 2; ++i2) {
        const int row = wr + i2 * 16 + ll;
        af[i2] = ldfrag(&sA[row * 64 + ((sub * 4 + lg) ^ (row & 7)) * 8]);
      }
#pragma unroll
      for (int j2 = 0; j2 < 2; ++j2) {
        const int row = wc + j2 * 16 + ll;
        bfr[j2] = ldfrag(&sB[row * 64 + ((sub * 4 + lg) ^ (row & 7)) * 8]);
      }
#pragma unroll
      for (int i2 = 0; i2 < 2; ++i2)
#pragma unroll
        for (int j2 = 0; j2 < 2; ++j2)
          acc[i2][j2] = mfma16(af[i2], bfr[j2], acc[i2][j2]);
    }
  }

#pragma unroll
  for (int j2 = 0; j2 < 2; ++j2) {
    const int ncol = nb * 64 + wc + j2 * 16 + ll;
    const float bb = bo[ncol];
#pragma unroll
    for (int i2 = 0; i2 < 2; ++i2) {
#pragma unroll
      for (int r = 0; r < 4; ++r) {
        const int mrow = mb * 64 + wr + i2 * 16 + lg * 4 + r;
        out[(size_t)mrow * DEMB + ncol] = acc[i2][j2][r] + bb;
      }
    }
  }
}

extern "C" void kernel_launch(void* const* d_in, const int* in_sizes, int n_in,
                              void* d_out, int out_size, void* d_ws,
                              size_t ws_size, hipStream_t stream) {
  (void)in_sizes; (void)n_in; (void)out_size; (void)ws_size;
  const float* Q  = (const float*)d_in[0];
  const float* K  = (const float*)d_in[1];
  const float* V  = (const float*)d_in[2];
  const float* WQ = (const float*)d_in[3];
  const float* bQ = (const float*)d_in[4];
  const float* WK = (const float*)d_in[5];
  const float* bK = (const float*)d_in[6];
  const float* WV = (const float*)d_in[7];
  const float* bV = (const float*)d_in[8];
  const float* WO = (const float*)d_in[9];
  const float* bO = (const float*)d_in[10];
  float* out = (float*)d_out;

  // workspace (u16 units): 4M(Wqkv+Wo) + 12M(qin/kin/vin) + 16M(qh/kh/vt/ctx)
  // = 32M u16 = 64 MiB.  After qkv_gemm, qin (8M needed) and Wqkv (512K
  // needed) are dead -> reused as attention partial buffers (no ws growth).
  u16* ws   = (u16*)d_ws;
  u16* Wqkv = ws;                        // [3072,1024]
  u16* Wo   = Wqkv + 3072 * 1024;        // [1024,1024]
  u16* qin  = Wo + 1024 * 1024;          // [4096,1024] bf16 activations
  u16* kin  = qin + (size_t)MTOT * DEMB;
  u16* vin  = kin + (size_t)MTOT * DEMB;
  u16* qh   = vin + (size_t)MTOT * DEMB; // [BH=32][S=2048][64] (pre-scaled)
  u16* kh   = qh + 32 * 2048 * 64;       // [BH][S][64]
  u16* vt   = kh + 32 * 2048 * 64;       // [BH][64][S] (transposed)
  u16* ctx  = vt + 32 * 2048 * 64;       // [B][S][H][64] == [4096,1024]
  u16* opart   = qin;                    // alias: [2][32][2048][64] bf16 = 8M
  float* lpart = (float*)Wqkv;           // alias: [2][32][2048] f32 = 512 KB

  const int WN = DEMB * DEMB;            // 1,048,576
  const int AN = MTOT * DEMB;            // 4,194,304
  cvt_bf16<<<WN / 1024, 256, 0, stream>>>(WQ, Wqkv, WN);
  cvt_bf16<<<WN / 1024, 256, 0, stream>>>(WK, Wqkv + WN, WN);
  cvt_bf16<<<WN / 1024, 256, 0, stream>>>(WV, Wqkv + 2 * WN, WN);
  cvt_bf16<<<WN / 1024, 256, 0, stream>>>(WO, Wo, WN);
  cvt_bf16<<<AN / 1024, 256, 0, stream>>>(Q, qin, AN);
  cvt_bf16<<<AN / 1024, 256, 0, stream>>>(K, kin, AN);
  cvt_bf16<<<AN / 1024, 256, 0, stream>>>(V, vin, AN);

  qkv_gemm<<<dim3(24, 32), 256, 0, stream>>>(qin, kin, vin, Wqkv, bQ, bK, bV,
                                             qh, kh, vt);
  attn_kernel<<<dim3(32, 32), 256, 0, stream>>>(qh, kh, vt, opart, lpart);
  merge_ctx<<<2048, 256, 0, stream>>>(opart, lpart, ctx);
  out_gemm<<<dim3(16, 64), 256, 0, stream>>>(ctx, Wo, bO, out);
}

// Round 8
// 238.996 us; speedup vs baseline: 1.0514x; 1.0514x over previous
//
#include <hip/hip_runtime.h>
#include <cstdint>
#include <cstddef>

// Problem constants: B=2, S=2048, D=1024, H=16, dk=64. M = B*S = 4096.
#define S_LEN 2048
#define NH    16
#define DKH   64
#define DEMB  1024
#define MTOT  4096

typedef float f32x4 __attribute__((ext_vector_type(4)));
typedef __bf16 bf16x8 __attribute__((ext_vector_type(8)));
typedef _Float16 f16;
typedef f16 f16x2 __attribute__((ext_vector_type(2)));
typedef f16 f16x4 __attribute__((ext_vector_type(4)));
typedef unsigned short u16;
typedef unsigned int u32;
typedef u16 u16x8 __attribute__((ext_vector_type(8)));
typedef u16 u16x4 __attribute__((ext_vector_type(4)));

static __device__ __forceinline__ u16 f2bf(float f) {
  u32 u = __builtin_bit_cast(u32, f);
  u += 0x7fffu + ((u >> 16) & 1u);          // RNE
  return (u16)(u >> 16);
}
static __device__ __forceinline__ float bf2f(u16 b) {
  return __builtin_bit_cast(float, ((u32)b) << 16);
}
static __device__ __forceinline__ bf16x8 ldfrag(const u16* p) {
  return __builtin_bit_cast(bf16x8, *(const u16x8*)p);
}
static __device__ __forceinline__ f16x4 ldfragh(const u16* p) {
  return __builtin_bit_cast(f16x4, *(const u16x4*)p);
}
static __device__ __forceinline__ f32x4 mfma16(bf16x8 a, bf16x8 b, f32x4 c) {
  return __builtin_amdgcn_mfma_f32_16x16x32_bf16(a, b, c, 0, 0, 0);
}
static __device__ __forceinline__ f32x4 mfmah(f16x4 a, f16x4 b, f32x4 c) {
  return __builtin_amdgcn_mfma_f32_16x16x16f16(a, b, c, 0, 0, 0);
}
static __device__ __forceinline__ void gl2lds16(const void* g, void* l) {
  __builtin_amdgcn_global_load_lds((__attribute__((address_space(1))) void*)g,
                                   (__attribute__((address_space(3))) void*)l,
                                   16, 0, 0);
}
// pack 4 fp32 -> 4 f16 (RTZ) via 2 v_cvt_pkrtz
static __device__ __forceinline__ f16x4 pkh4(float a, float b, float c, float d) {
  f16x2 lo = __builtin_bit_cast(f16x2, __builtin_amdgcn_cvt_pkrtz(a, b));
  f16x2 hi = __builtin_bit_cast(f16x2, __builtin_amdgcn_cvt_pkrtz(c, d));
  return __builtin_shufflevector(lo, hi, 0, 1, 2, 3);
}

// 1/sqrt(dk) * log2(e): folded into the Q projection so attention scores are
// already in the exp2 domain.
#define SCL_Q (0.125f * 1.44269504088896340736f)

// ---------------- fused fp32 -> bf16 convert (all 7 tensors, 1 launch) -------
// blocks 0..4095: weights (WQ,WK,WV,WO -> dW contiguous, 1024 blocks each)
// blocks 4096..16383: activations (Q,K,V -> dA contiguous, 4096 blocks each)
__global__ __launch_bounds__(256) void cvt_all(
    const float* __restrict__ wq, const float* __restrict__ wk,
    const float* __restrict__ wv, const float* __restrict__ wo,
    const float* __restrict__ q, const float* __restrict__ k,
    const float* __restrict__ v, u16* __restrict__ dW, u16* __restrict__ dA) {
  int b = blockIdx.x;
  const float* s; u16* d;
  if (b < 4096) {
    const int seg = b >> 10;
    s = (seg == 0) ? wq : (seg == 1) ? wk : (seg == 2) ? wv : wo;
    d = dW + (size_t)seg * (DEMB * DEMB);
    b &= 1023;
  } else {
    const int bb = b - 4096;
    const int seg = bb >> 12;
    s = (seg == 0) ? q : (seg == 1) ? k : v;
    d = dA + (size_t)seg * ((size_t)MTOT * DEMB);
    b = bb & 4095;
  }
  const int i = (b * 256 + threadIdx.x) * 4;
  f32x4 f = *(const f32x4*)(s + i);
  u16x4 o;
  o[0] = f2bf(f[0]); o[1] = f2bf(f[1]); o[2] = f2bf(f[2]); o[3] = f2bf(f[3]);
  *(u16x4*)(d + i) = o;
}

// ---------------- fused QKV projection GEMM (pure bf16, m97 structure) -------
// V output is written as f16 (RTZ) since the PV MFMA consumes f16.
__global__ __launch_bounds__(256) void qkv_gemm(
    const u16* __restrict__ qin, const u16* __restrict__ kin,
    const u16* __restrict__ vin, const u16* __restrict__ W,
    const float* __restrict__ bq, const float* __restrict__ bk,
    const float* __restrict__ bv,
    u16* __restrict__ qh, u16* __restrict__ kh, u16* __restrict__ vt) {
  __shared__ __align__(16) u16 sA[128 * 32];    // 8 KB
  __shared__ __align__(16) u16 sB[128 * 32];    // 8 KB
  const int t = threadIdx.x;
  const int l = t & 63, w = t >> 6;
  const int ll = l & 15, lg = l >> 4;
  const int nb = blockIdx.x;           // 0..23 (N = 3072)
  const int mb = blockIdx.y;           // 0..31 (M = 4096)
  const int which = nb >> 3;           // 0=Q,1=K,2=V
  const u16* A = (which == 0) ? qin : ((which == 1) ? kin : vin);
  const int wr = (w >> 1) * 64, wc = (w & 1) * 64;

  f32x4 acc[4][4] = {};

  for (int kt = 0; kt < 32; ++kt) {
    const int k0 = kt * 32;
    __syncthreads();
#pragma unroll
    for (int i = 0; i < 2; ++i) {
      const int c = i * 256 + t;                 // 16B chunk 0..511
      const int row = c >> 2;                    // 0..127
      const int gc = (c & 3) ^ ((row >> 1) & 3); // global col-chunk
      gl2lds16(A + (size_t)(mb * 128 + row) * DEMB + k0 + gc * 8, &sA[c * 8]);
      gl2lds16(W + (size_t)(nb * 128 + row) * DEMB + k0 + gc * 8, &sB[c * 8]);
    }
    __syncthreads();

    bf16x8 af[4], bfr[4];
#pragma unroll
    for (int i2 = 0; i2 < 4; ++i2) {
      const int row = wr + i2 * 16 + ll;
      af[i2] = ldfrag(&sA[row * 32 + (lg ^ ((row >> 1) & 3)) * 8]);
    }
#pragma unroll
    for (int j2 = 0; j2 < 4; ++j2) {
      const int row = wc + j2 * 16 + ll;
      bfr[j2] = ldfrag(&sB[row * 32 + (lg ^ ((row >> 1) & 3)) * 8]);
    }
#pragma unroll
    for (int i2 = 0; i2 < 4; ++i2)
#pragma unroll
      for (int j2 = 0; j2 < 4; ++j2)
        acc[i2][j2] = mfma16(af[i2], bfr[j2], acc[i2][j2]);
  }

  const float* bias = (which == 0) ? bq : ((which == 1) ? bk : bv);
  const int b = (mb * 128) >> 11;                // tile never crosses batch

  if (which == 2) {
    // V: f16 register scatter to [bh][dk][s]; 4 consecutive s per 8B store
#pragma unroll
    for (int j2 = 0; j2 < 4; ++j2) {
      const int nl = (nb * 128 + wc + j2 * 16 + ll) & 1023;
      const int h = nl >> 6, dk = nl & 63;
      const float bb = bias[nl];
      u16* base = vt + ((size_t)((b * NH + h) * DKH + dk)) * S_LEN;
#pragma unroll
      for (int i2 = 0; i2 < 4; ++i2) {
        const int s = (mb * 128 + wr + i2 * 16 + lg * 4) & 2047;
        const f16x4 pk = pkh4(acc[i2][j2][0] + bb, acc[i2][j2][1] + bb,
                              acc[i2][j2][2] + bb, acc[i2][j2][3] + bb);
        *(u16x4*)&base[s] = __builtin_bit_cast(u16x4, pk);
      }
    }
  } else {
    u16* outp = (which == 0) ? qh : kh;
    const float scl = (which == 0) ? SCL_Q : 1.0f;
#pragma unroll
    for (int j2 = 0; j2 < 4; ++j2) {
      const int nl = (nb * 128 + wc + j2 * 16 + ll) & 1023;
      const int h = nl >> 6, dk = nl & 63;
      const float bb = bias[nl];
#pragma unroll
      for (int i2 = 0; i2 < 4; ++i2) {
#pragma unroll
        for (int r = 0; r < 4; ++r) {
          const int s = (mb * 128 + wr + i2 * 16 + lg * 4 + r) & 2047;
          const float val = (acc[i2][j2][r] + bb) * scl;
          outp[((size_t)((b * NH + h) * S_LEN + s)) * DKH + dk] = f2bf(val);
        }
      }
    }
  }
}

// ---------------- flash attention, no-P-roundtrip formulation ----------------
// Grid (32,32): x = qb*2 + ks (key half), y = bh. 128 q rows x 1024 keys,
// KT=64. S^T = K.Q^T via 16x16x32 bf16 (C layout: key=lg*4+r, q=ll).
// KEY TRICK: that C layout is exactly the B-operand layout of the K=16 MFMA
// v_mfma_f32_16x16x16_f16 (B: n=l&15, k=lg*4+j), so exp2 results feed PV
// DIRECTLY from registers — no LDS P buffer, no cross-lane transform.
// PV: O^T += V^T(f16 A-frag, m=dk=ll, k=key=lg*4+j) . P(f16).
// Fixed-max exp2 softmax (Q pre-scaled) => key-split partials merge
// additively. LDS = sK 8K + sV 8K = 16 KB.
__global__ __launch_bounds__(256) void attn_kernel(
    const u16* __restrict__ qh, const u16* __restrict__ kh,
    const u16* __restrict__ vt, u16* __restrict__ opart,
    float* __restrict__ lpart) {
  __shared__ __align__(16) u16 sK[64 * 64];       // [key][dk]  8 KB bf16
  __shared__ __align__(16) u16 sV[64 * 64];       // [dk][key]  8 KB f16
  const int t = threadIdx.x;
  const int l = t & 63, w = t >> 6;
  const int ll = l & 15, lg = l >> 4;
  const int qb = blockIdx.x >> 1;
  const int ks = blockIdx.x & 1;
  const int q_blk = qb * 128;
  const int bh = blockIdx.y;

  // Q fragments (B-operand of 16x16x32: q=ll, dk=f*32+lg*8..+7)
  bf16x8 aq[2][2];
#pragma unroll
  for (int qt = 0; qt < 2; ++qt) {
    const u16* qbase = qh + ((size_t)bh * S_LEN + q_blk + w * 32 + qt * 16 + ll) * DKH;
    aq[qt][0] = ldfrag(qbase + lg * 8);
    aq[qt][1] = ldfrag(qbase + 32 + lg * 8);
  }

  f32x4 oT[2][4] = {};        // [qt][dk-tile]; C layout: q=ll, dk=nt*16+lg*4+r
  float l_part[2] = {0.f, 0.f};

  for (int kt = 0; kt < 16; ++kt) {
    const int kb0 = ks * 1024 + kt * 64;
    __syncthreads();
#pragma unroll
    for (int i = 0; i < 2; ++i) {
      const int c = i * 256 + t;                  // 16B chunk 0..511
      const int row = c >> 3, gc = (c & 7) ^ (row & 7);
      // sK: [key 0..63][8 chunks of dk], swizzle chunk ^ (row&7)
      gl2lds16(kh + ((size_t)bh * S_LEN + kb0 + row) * DKH + gc * 8,
               &sK[c * 8]);
      // sV: [dk 0..63][8 chunks of keys], swizzle chunk ^ (row&7)
      gl2lds16(vt + ((size_t)bh * DKH + row) * S_LEN + kb0 + gc * 8,
               &sV[c * 8]);
    }
    __syncthreads();

#pragma unroll
    for (int kbl = 0; kbl < 4; ++kbl) {
      // ---- S^T for 16 keys x 32 q ----
      const int krow = kbl * 16 + ll;
      const bf16x8 ak0 = ldfrag(&sK[krow * 64 + (lg ^ (ll & 7)) * 8]);
      const bf16x8 ak1 = ldfrag(&sK[krow * 64 + ((4 + lg) ^ (ll & 7)) * 8]);
      f32x4 s0 = {}, s1 = {};
      s0 = mfma16(ak0, aq[0][0], s0);
      s0 = mfma16(ak1, aq[0][1], s0);
      s1 = mfma16(ak0, aq[1][0], s1);
      s1 = mfma16(ak1, aq[1][1], s1);

      // ---- softmax numerators, packed straight into PV B-operands ----
      f16x4 bp0, bp1;
      {
        const float p0 = __builtin_amdgcn_exp2f(s0[0]);
        const float p1 = __builtin_amdgcn_exp2f(s0[1]);
        const float p2 = __builtin_amdgcn_exp2f(s0[2]);
        const float p3 = __builtin_amdgcn_exp2f(s0[3]);
        l_part[0] += (p0 + p1) + (p2 + p3);
        bp0 = pkh4(p0, p1, p2, p3);
      }
      {
        const float p0 = __builtin_amdgcn_exp2f(s1[0]);
        const float p1 = __builtin_amdgcn_exp2f(s1[1]);
        const float p2 = __builtin_amdgcn_exp2f(s1[2]);
        const float p3 = __builtin_amdgcn_exp2f(s1[3]);
        l_part[1] += (p0 + p1) + (p2 + p3);
        bp1 = pkh4(p0, p1, p2, p3);
      }

      // ---- O^T += V^T . P  (16x16x16 f16, K=16 keys of this kbl) ----
#pragma unroll
      for (int nt = 0; nt < 4; ++nt) {
        const int row = nt * 16 + ll;             // dk row of sV
        // 8B frag: keys kbl*16 + lg*4..+3 at swizzled chunk
        const int ch = (kbl * 2 + (lg >> 1)) ^ (ll & 7);
        const f16x4 av = ldfragh(&sV[row * 64 + ch * 8 + (lg & 1) * 4]);
        oT[0][nt] = mfmah(av, bp0, oT[0][nt]);
        oT[1][nt] = mfmah(av, bp1, oT[1][nt]);
      }
    }
  }

  // ---- store unnormalized partials ----
#pragma unroll
  for (int qt = 0; qt < 2; ++qt) {
    float lv = l_part[qt];
    lv += __shfl_xor(lv, 16, 64);
    lv += __shfl_xor(lv, 32, 64);
    const int srow = q_blk + w * 32 + qt * 16 + ll;
    u16* obase = opart + (((size_t)(ks * 32 + bh)) * S_LEN + srow) * DKH;
#pragma unroll
    for (int nt = 0; nt < 4; ++nt) {
      u16x4 o;
#pragma unroll
      for (int r = 0; r < 4; ++r) o[r] = f2bf(oT[qt][nt][r]);
      *(u16x4*)&obase[nt * 16 + lg * 4] = o;
    }
    if (lg == 0) lpart[(ks * 32 + bh) * S_LEN + srow] = lv;
  }
}

// ---------------- merge partials -> ctx ----------------
// ctx[b][s][h][dk] = (O0 + O1) / (l0 + l1)
__global__ __launch_bounds__(256) void merge_ctx(
    const u16* __restrict__ op, const float* __restrict__ lp,
    u16* __restrict__ ctx) {
  const int idx = blockIdx.x * 256 + threadIdx.x;   // 0..524287
  const int dk8 = idx & 7;
  const int q = (idx >> 3) & 2047;
  const int bh = idx >> 14;                         // 0..31
  const float inv = 1.0f / (lp[bh * S_LEN + q] + lp[(32 + bh) * S_LEN + q]);
  const u16x8 a = *(const u16x8*)&op[((size_t)bh * S_LEN + q) * DKH + dk8 * 8];
  const u16x8 c = *(const u16x8*)&op[((size_t)(32 + bh) * S_LEN + q) * DKH + dk8 * 8];
  u16x8 o;
#pragma unroll
  for (int r = 0; r < 8; ++r) o[r] = f2bf((bf2f(a[r]) + bf2f(c[r])) * inv);
  const int b = bh >> 4, h = bh & 15;
  *(u16x8*)&ctx[((size_t)((b * S_LEN + q) * NH + h)) * DKH + dk8 * 8] = o;
}

// ---------------- output projection GEMM ----------------
// 64x64 tile, BK=64, 4 waves (2x2 of 32x32). Grid (16,64) = 1024 blocks
// = 4 blocks/CU -> ~16 waves/CU for latency hiding.
__global__ __launch_bounds__(256) void out_gemm(
    const u16* __restrict__ Am, const u16* __restrict__ W,
    const float* __restrict__ bo, float* __restrict__ out) {
  __shared__ __align__(16) u16 sA[64 * 64];   // 8 KB
  __shared__ __align__(16) u16 sB[64 * 64];   // 8 KB
  const int t = threadIdx.x;
  const int l = t & 63, w = t >> 6;
  const int ll = l & 15, lg = l >> 4;
  const int nb = blockIdx.x;  // 0..15
  const int mb = blockIdx.y;  // 0..63
  const int wr = (w >> 1) * 32, wc = (w & 1) * 32;

  f32x4 acc[2][2] = {};
  for (int kt = 0; kt < 16; ++kt) {
    const int k0 = kt * 64;
    __syncthreads();
#pragma unroll
    for (int i = 0; i < 2; ++i) {
      const int c = i * 256 + t;               // 512 chunks per buffer
      const int row = c >> 3;
      const int gc = (c & 7) ^ (row & 7);
      gl2lds16(Am + (size_t)(mb * 64 + row) * DEMB + k0 + gc * 8, &sA[c * 8]);
      gl2lds16(W + (size_t)(nb * 64 + row) * DEMB + k0 + gc * 8, &sB[c * 8]);
    }
    __syncthreads();
#pragma unroll
    for (int sub = 0; sub < 2; ++sub) {
      bf16x8 af[2], bfr[2];
#pragma unroll
      for (int i2 = 0; i2 < 2; ++i2) {
        const int row = wr + i2 * 16 + ll;
        af[i2] = ldfrag(&sA[row * 64 + ((sub * 4 + lg) ^ (row & 7)) * 8]);
      }
#pragma unroll
      for (int j2 = 0; j2 < 2; ++j2) {
        const int row = wc + j2 * 16 + ll;
        bfr[j2] = ldfrag(&sB[row * 64 + ((sub * 4 + lg) ^ (row & 7)) * 8]);
      }
#pragma unroll
      for (int i2 = 0; i2 < 2; ++i2)
#pragma unroll
        for (int j2 = 0; j2 < 2; ++j2)
          acc[i2][j2] = mfma16(af[i2], bfr[j2], acc[i2][j2]);
    }
  }

#pragma unroll
  for (int j2 = 0; j2 < 2; ++j2) {
    const int ncol = nb * 64 + wc + j2 * 16 + ll;
    const float bb = bo[ncol];
#pragma unroll
    for (int i2 = 0; i2 < 2; ++i2) {
#pragma unroll
      for (int r = 0; r < 4; ++r) {
        const int mrow = mb * 64 + wr + i2 * 16 + lg * 4 + r;
        out[(size_t)mrow * DEMB + ncol] = acc[i2][j2][r] + bb;
      }
    }
  }
}

extern "C" void kernel_launch(void* const* d_in, const int* in_sizes, int n_in,
                              void* d_out, int out_size, void* d_ws,
                              size_t ws_size, hipStream_t stream) {
  (void)in_sizes; (void)n_in; (void)out_size; (void)ws_size;
  const float* Q  = (const float*)d_in[0];
  const float* K  = (const float*)d_in[1];
  const float* V  = (const float*)d_in[2];
  const float* WQ = (const float*)d_in[3];
  const float* bQ = (const float*)d_in[4];
  const float* WK = (const float*)d_in[5];
  const float* bK = (const float*)d_in[6];
  const float* WV = (const float*)d_in[7];
  const float* bV = (const float*)d_in[8];
  const float* WO = (const float*)d_in[9];
  const float* bO = (const float*)d_in[10];
  float* out = (float*)d_out;

  // workspace (u16 units): 4M(Wqkv+Wo) + 12M(qin/kin/vin) + 16M(qh/kh/vt/ctx)
  // = 32M u16 = 64 MiB.  After qkv_gemm, qin and Wqkv are dead -> reused as
  // attention partial buffers (no ws growth).
  u16* ws   = (u16*)d_ws;
  u16* Wqkv = ws;                        // [3072,1024] (+Wo contiguous after)
  u16* Wo   = Wqkv + 3072 * 1024;        // [1024,1024]
  u16* qin  = Wo + 1024 * 1024;          // [4096,1024] bf16 activations
  u16* kin  = qin + (size_t)MTOT * DEMB;
  u16* vin  = kin + (size_t)MTOT * DEMB;
  u16* qh   = vin + (size_t)MTOT * DEMB; // [BH=32][S=2048][64] (pre-scaled)
  u16* kh   = qh + 32 * 2048 * 64;       // [BH][S][64]
  u16* vt   = kh + 32 * 2048 * 64;       // [BH][64][S] (transposed, f16)
  u16* ctx  = vt + 32 * 2048 * 64;       // [B][S][H][64] == [4096,1024]
  u16* opart   = qin;                    // alias: [2][32][2048][64] bf16 = 8M
  float* lpart = (float*)Wqkv;           // alias: [2][32][2048] f32 = 512 KB

  cvt_all<<<16384, 256, 0, stream>>>(WQ, WK, WV, WO, Q, K, V, Wqkv, qin);

  qkv_gemm<<<dim3(24, 32), 256, 0, stream>>>(qin, kin, vin, Wqkv, bQ, bK, bV,
                                             qh, kh, vt);
  attn_kernel<<<dim3(32, 32), 256, 0, stream>>>(qh, kh, vt, opart, lpart);
  merge_ctx<<<2048, 256, 0, stream>>>(opart, lpart, ctx);
  out_gemm<<<dim3(16, 64), 256, 0, stream>>>(ctx, Wo, bO, out);
}